// Round 2
// baseline (333.243 us; speedup 1.0000x reference)
//
#include <hip/hip_runtime.h>
#include <hip/hip_bf16.h>

// Swin shifted-window attention, MI355X gfx950.
// B=8, H=W=128, D=256, NHEAD=8, DK=32, WS=8, NH=NW=16, WSQ=64, SHIFT=4.
// All global I/O is float32; compute is bf16 MFMA with f32 accumulation.
// Pipeline: prep (Wt transpose->bf16 + ADD table) -> GEMM_Q -> GEMM_KV -> attn
//           (attn overwrites Qp with its output, same windowed layout) -> GEMM_O.

typedef __bf16  bf16x8 __attribute__((ext_vector_type(8)));
typedef short   short8 __attribute__((ext_vector_type(8)));
typedef float   f32x4  __attribute__((ext_vector_type(4)));

#define SCALE_F 0.17677669529663687f

__device__ __forceinline__ short f2bs(float f){
    __hip_bfloat16 h = __float2bfloat16(f);
    return __builtin_bit_cast(short, h);
}
// region strip: class 0 = interior; class 1 = wi==14; class 2 = wi==15
__device__ __forceinline__ int strip3(int r, int c){
    if (c == 0) return 0;
    if (c == 1) return (r < 4) ? 0 : 1;
    return (r < 4) ? 2 : 0;
}

// ---------------- prep: weight transpose->bf16 + fused (mask | rel-pos-bias) table
__global__ __launch_bounds__(256) void prep_k(const float* __restrict__ Wq,
                                              const float* __restrict__ Wkv,
                                              const float* __restrict__ Wo,
                                              const float* __restrict__ rel,
                                              short* __restrict__ Wqt,
                                              short* __restrict__ Wkvt,
                                              short* __restrict__ Wot,
                                              float* __restrict__ ADD){
    int i = blockIdx.x * 256 + threadIdx.x;
    if (i < 65536){                       // Wqt[n][k] = bf16(Wq[k][n])
        int n = i >> 8, k = i & 255;
        Wqt[i] = f2bs(Wq[k * 256 + n]);
    } else if (i < 196608){               // Wkvt[n][k] = bf16(Wkv[k][n]), n<512
        int j = i - 65536;
        int n = j >> 8, k = j & 255;
        Wkvt[j] = f2bs(Wkv[k * 512 + n]);
    } else if (i < 262144){               // Wot
        int j = i - 196608;
        int n = j >> 8, k = j & 255;
        Wot[j] = f2bs(Wo[k * 256 + n]);
    } else {                              // ADD[cls][head][q][k], 9*8*64*64 f32
        int j = i - 262144;
        int k = j & 63, q = (j >> 6) & 63, head = (j >> 12) & 7, cls = j >> 15;
        int wiC = cls / 3, wjC = cls - wiC * 3;
        int qr = q >> 3, qc = q & 7, kr = k >> 3, kc = k & 7;
        int lq = strip3(qr, wiC) * 3 + strip3(qc, wjC);
        int lk = strip3(kr, wiC) * 3 + strip3(kc, wjC);
        float pe = rel[((qr - kr + 7) * 15 + (qc - kc + 7)) * 8 + head];
        ADD[j] = (lq != lk) ? -1e9f : pe;
    }
}

// ---------------- projection GEMM: C[M,N] = A[M,256] @ Wt^T + bias ----------
// MODE 0: A=x (f32),  N=256, store permuted bf16 -> Qp
// MODE 1: A=z (f32),  N=512, store permuted bf16 -> Kp (col<256) / Vp (col>=256)
// MODE 2: A=att (bf16, windowed layout in Qp), N=256, store f32 -> d_out
template<int MODE>
__global__ __launch_bounds__(256) void gemm_k(const void* __restrict__ Agv,
                                              const short* __restrict__ Btg,
                                              const float* __restrict__ bias,
                                              void* __restrict__ out0v,
                                              short* __restrict__ out1){
    __shared__ __align__(16) short As[64 * 40];    // pitch 40 (b128-aligned)
    __shared__ __align__(16) short Bs[128 * 40];
    const int tid = threadIdx.x, w = tid >> 6, lane = tid & 63;
    const int l15 = lane & 15, g = lane >> 4;
    const int m0 = blockIdx.x * 64, n0 = blockIdx.y * 128;

    // pixel decomposition for this block's 64 consecutive rows
    const int b = m0 >> 14;
    const int rem = m0 & 16383;
    const int r_img = rem >> 7;
    const int c0 = rem & 127;
    const int rr = (r_img + 124) & 127;        // shifted row
    const int wi = rr >> 3, qr = rr & 7;

    f32x4 acc[4][2];
    const f32x4 zero = {0.f, 0.f, 0.f, 0.f};
#pragma unroll
    for (int mi = 0; mi < 4; ++mi)
#pragma unroll
        for (int nj = 0; nj < 2; ++nj) acc[mi][nj] = zero;

    const int arow = tid >> 2, ach = tid & 3;      // A: 64 rows x 4 chunks of 8
    // MODE 2: windowed A source offset (head term added per kt)
    size_t awoff = 0;
    if (MODE == 2){
        const int cc = (c0 + arow + 124) & 127;
        const int wj = cc >> 3, qc = cc & 7;
        awoff = ((((size_t)b * 8) * 16 + wi) * 16 + wj) * 2048 + (size_t)(qr * 8 + qc) * 32 + ach * 8;
    }

    for (int kt = 0; kt < 8; ++kt){
        const int k0 = kt * 32;
        short8 as8;
        if (MODE == 2){
            const short* Ag = (const short*)Agv;
            as8 = *reinterpret_cast<const short8*>(Ag + awoff + (size_t)kt * 524288);
        } else {
            const float* Ag = (const float*)Agv;
            const float* ap = Ag + (size_t)(m0 + arow) * 256 + k0 + ach * 8;
            float4 a0 = *reinterpret_cast<const float4*>(ap);
            float4 a1 = *reinterpret_cast<const float4*>(ap + 4);
            as8[0] = f2bs(a0.x); as8[1] = f2bs(a0.y); as8[2] = f2bs(a0.z); as8[3] = f2bs(a0.w);
            as8[4] = f2bs(a1.x); as8[5] = f2bs(a1.y); as8[6] = f2bs(a1.z); as8[7] = f2bs(a1.w);
        }
        int4 br0 = *reinterpret_cast<const int4*>(Btg + (size_t)(n0 + (tid >> 2)) * 256 + k0 + (tid & 3) * 8);
        const int c1 = tid + 256;
        int4 br1 = *reinterpret_cast<const int4*>(Btg + (size_t)(n0 + (c1 >> 2)) * 256 + k0 + (c1 & 3) * 8);
        __syncthreads();
        *reinterpret_cast<short8*>(&As[arow * 40 + ach * 8]) = as8;
        *reinterpret_cast<int4*>(&Bs[(tid >> 2) * 40 + (tid & 3) * 8]) = br0;
        *reinterpret_cast<int4*>(&Bs[(c1 >> 2) * 40 + (c1 & 3) * 8]) = br1;
        __syncthreads();

        bf16x8 af[4], bfr[2];
#pragma unroll
        for (int mi = 0; mi < 4; ++mi)
            af[mi] = *reinterpret_cast<const bf16x8*>(&As[(mi * 16 + l15) * 40 + g * 8]);
#pragma unroll
        for (int nj = 0; nj < 2; ++nj)
            bfr[nj] = *reinterpret_cast<const bf16x8*>(&Bs[(w * 32 + nj * 16 + l15) * 40 + g * 8]);
#pragma unroll
        for (int mi = 0; mi < 4; ++mi)
#pragma unroll
            for (int nj = 0; nj < 2; ++nj)
                acc[mi][nj] = __builtin_amdgcn_mfma_f32_16x16x32_bf16(af[mi], bfr[nj], acc[mi][nj], 0, 0, 0);
    }

    const int colbase = n0 + w * 32;
    if (MODE == 2){
        float* outF = (float*)out0v;
#pragma unroll
        for (int mi = 0; mi < 4; ++mi)
#pragma unroll
            for (int nj = 0; nj < 2; ++nj){
                int col = colbase + nj * 16 + l15;
                float bv = bias[col];
#pragma unroll
                for (int r = 0; r < 4; ++r){
                    int row = m0 + mi * 16 + g * 4 + r;
                    outF[(size_t)row * 256 + col] = acc[mi][nj][r] + bv;
                }
            }
    } else {
        short* out0 = (short*)out0v;
#pragma unroll
        for (int mi = 0; mi < 4; ++mi)
#pragma unroll
            for (int nj = 0; nj < 2; ++nj){
                int col = colbase + nj * 16 + l15;
                float bv = bias[col];
                short* dst; int head;
                if (MODE == 1 && col >= 256){ dst = out1; head = (col >> 5) - 8; }
                else { dst = out0; head = col >> 5; }
                const int dk = col & 31;
                const size_t hb = (((size_t)b * 8 + head) * 16 + wi) * 16;
#pragma unroll
                for (int r = 0; r < 4; ++r){
                    int local = mi * 16 + g * 4 + r;
                    int cc = (c0 + local + 124) & 127;   // shifted col
                    int wj = cc >> 3, qc = cc & 7;
                    size_t off = ((hb + wj) * 64 + qr * 8 + qc) * 32 + dk;
                    dst[off] = f2bs(acc[mi][nj][r] + bv);
                }
            }
    }
}

// ---------------- windowed attention: 1 block per (b,wi,wj), 2 heads/wave ------
// Writes output INTO Qp (same windowed layout) — each wave overwrites exactly
// the Q window it consumed this iteration; head-windows are wave-disjoint.
__global__ __launch_bounds__(256) void attn_k(short* __restrict__ Qp,
                                              const short* __restrict__ Kp,
                                              const short* __restrict__ Vp,
                                              const float* __restrict__ ADD){
    __shared__ __align__(16) short Pl[4][64 * 72];   // per-wave P (bf16, pitch 72)
    __shared__ __align__(16) short Vl[4][64 * 36];   // per-wave V (bf16, pitch 36)
    const int tid = threadIdx.x, w = tid >> 6, lane = tid & 63;
    const int l15 = lane & 15, g = lane >> 4;
    const int bx = blockIdx.x;
    const int wj = bx & 15, wi = (bx >> 4) & 15, b = bx >> 8;
    const int wiC = (wi > 13) ? wi - 13 : 0;
    const int wjC = (wj > 13) ? wj - 13 : 0;
    short* P  = &Pl[w][0];
    short* VL = &Vl[w][0];
    const f32x4 zero = {0.f, 0.f, 0.f, 0.f};

    for (int hh = 0; hh < 2; ++hh){
        const int head = w + hh * 4;
        const size_t win = ((((size_t)b * 8 + head) * 16 + wi) * 16 + wj) * 2048;

        // stage V rows (lane = key) into LDS, pitch 36
        const int4* vsrc = reinterpret_cast<const int4*>(Vp + win + lane * 32);
#pragma unroll
        for (int ch = 0; ch < 4; ++ch){
            int4 vv = vsrc[ch];
            *reinterpret_cast<int2*>(&VL[lane * 36 + ch * 8])     = make_int2(vv.x, vv.y);
            *reinterpret_cast<int2*>(&VL[lane * 36 + ch * 8 + 4]) = make_int2(vv.z, vv.w);
        }

        // QK^T: scores 64x64 in registers
        bf16x8 aq[4], bk[4];
        const short* Qw = Qp + win;
        const short* Kw = Kp + win;
#pragma unroll
        for (int mi = 0; mi < 4; ++mi)
            aq[mi] = *reinterpret_cast<const bf16x8*>(Qw + (mi * 16 + l15) * 32 + g * 8);
#pragma unroll
        for (int ni = 0; ni < 4; ++ni)
            bk[ni] = *reinterpret_cast<const bf16x8*>(Kw + (ni * 16 + l15) * 32 + g * 8);
        f32x4 s[4][4];
#pragma unroll
        for (int mi = 0; mi < 4; ++mi)
#pragma unroll
            for (int ni = 0; ni < 4; ++ni){
                s[mi][ni] = zero;
                s[mi][ni] = __builtin_amdgcn_mfma_f32_16x16x32_bf16(aq[mi], bk[ni], s[mi][ni], 0, 0, 0);
            }

        // scale + (mask|bias), wave-parallel softmax per q-row, P (unnormalized) -> LDS
        const float* addb = ADD + ((((wiC * 3 + wjC) * 8 + head)) << 12);
        float rs[4][4];
#pragma unroll
        for (int mi = 0; mi < 4; ++mi){
            const int qbase = mi * 16 + g * 4;
#pragma unroll
            for (int ni = 0; ni < 4; ++ni){
                const int k = ni * 16 + l15;
#pragma unroll
                for (int r = 0; r < 4; ++r)
                    s[mi][ni][r] = fmaf(s[mi][ni][r], SCALE_F, addb[((qbase + r) << 6) + k]);
            }
#pragma unroll
            for (int r = 0; r < 4; ++r){
                float m = fmaxf(fmaxf(s[mi][0][r], s[mi][1][r]), fmaxf(s[mi][2][r], s[mi][3][r]));
                m = fmaxf(m, __shfl_xor(m, 1));
                m = fmaxf(m, __shfl_xor(m, 2));
                m = fmaxf(m, __shfl_xor(m, 4));
                m = fmaxf(m, __shfl_xor(m, 8));
                float sum = 0.f;
#pragma unroll
                for (int ni = 0; ni < 4; ++ni){
                    float p = __expf(s[mi][ni][r] - m);
                    s[mi][ni][r] = p;
                    sum += p;
                }
                sum += __shfl_xor(sum, 1);
                sum += __shfl_xor(sum, 2);
                sum += __shfl_xor(sum, 4);
                sum += __shfl_xor(sum, 8);
                rs[mi][r] = 1.f / sum;
                const int q = qbase + r;
#pragma unroll
                for (int ni = 0; ni < 4; ++ni)
                    P[q * 72 + ni * 16 + l15] = f2bs(s[mi][ni][r]);
            }
        }

        // PV: out[64][32] = P @ V
        f32x4 o[4][2];
#pragma unroll
        for (int mi = 0; mi < 4; ++mi)
#pragma unroll
            for (int nj = 0; nj < 2; ++nj) o[mi][nj] = zero;
#pragma unroll
        for (int ks = 0; ks < 2; ++ks){
            bf16x8 pa[4];
#pragma unroll
            for (int mi = 0; mi < 4; ++mi)
                pa[mi] = *reinterpret_cast<const bf16x8*>(&P[(mi * 16 + l15) * 72 + ks * 32 + g * 8]);
            bf16x8 vb[2];
#pragma unroll
            for (int nj = 0; nj < 2; ++nj){
                short8 t;
#pragma unroll
                for (int j = 0; j < 8; ++j)
                    t[j] = VL[(ks * 32 + g * 8 + j) * 36 + nj * 16 + l15];
                vb[nj] = __builtin_bit_cast(bf16x8, t);
            }
#pragma unroll
            for (int mi = 0; mi < 4; ++mi)
#pragma unroll
                for (int nj = 0; nj < 2; ++nj)
                    o[mi][nj] = __builtin_amdgcn_mfma_f32_16x16x32_bf16(pa[mi], vb[nj], o[mi][nj], 0, 0, 0);
        }

        // normalize + store back into the SAME window (windowed att layout)
#pragma unroll
        for (int mi = 0; mi < 4; ++mi)
#pragma unroll
            for (int nj = 0; nj < 2; ++nj)
#pragma unroll
                for (int r = 0; r < 4; ++r){
                    const int q = mi * 16 + g * 4 + r;
                    Qp[win + (size_t)q * 32 + nj * 16 + l15] = f2bs(o[mi][nj][r] * rs[mi][r]);
                }
    }
}

extern "C" void kernel_launch(void* const* d_in, const int* in_sizes, int n_in,
                              void* d_out, int out_size, void* d_ws, size_t ws_size,
                              hipStream_t stream) {
    const float* x    = (const float*)d_in[0];
    const float* z    = (const float*)d_in[1];
    const float* Wq   = (const float*)d_in[2];
    const float* bq   = (const float*)d_in[3];
    const float* Wkv  = (const float*)d_in[4];
    const float* bkv  = (const float*)d_in[5];
    const float* Wo   = (const float*)d_in[6];
    const float* bo   = (const float*)d_in[7];
    const float* rel  = (const float*)d_in[8];

    char* ws = (char*)d_ws;
    short* Qp   = (short*)(ws);                       // 33.5M bf16 = 64 MiB (reused as att)
    short* Kp   = (short*)(ws + 67108864);            // 64 MiB
    short* Vp   = (short*)(ws + 134217728);           // 64 MiB
    short* Wqt  = (short*)(ws + 201326592);           // 128 KiB
    short* Wkvt = (short*)(ws + 201326592 + 131072);  // 256 KiB
    short* Wot  = (short*)(ws + 201326592 + 393216);  // 128 KiB
    float* ADD  = (float*)(ws + 201326592 + 524288);  // 1.125 MiB

    prep_k<<<2176, 256, 0, stream>>>(Wq, Wkv, Wo, rel, Wqt, Wkvt, Wot, ADD);
    gemm_k<0><<<dim3(2048, 2), 256, 0, stream>>>(x, Wqt, bq, Qp, nullptr);
    gemm_k<1><<<dim3(2048, 4), 256, 0, stream>>>(z, Wkvt, bkv, Kp, Vp);
    attn_k<<<2048, 256, 0, stream>>>(Qp, Kp, Vp, ADD);
    gemm_k<2><<<dim3(2048, 2), 256, 0, stream>>>(Qp, Wot, bo, d_out, nullptr);
}